// Round 1
// baseline (726.370 us; speedup 1.0000x reference)
//
#include <hip/hip_runtime.h>
#include <math.h>

#define N_NODES 50000
#define IN_F    256
#define HID     128
#define HEADS   4
#define NE      800000
#define ALPHA   0.2f
#define LN_EPS  1e-6f
#define OUT_F   512   // HEADS*HID

// ---------------- GEMM: X[n, h*128+j] = emb[n,:] . W[h,j,:] + b[h,j] ----------------
// W flat [HEADS][HID][IN] row-major == [512][256] row-major (Bt), exactly what we need.
// emb row 0 is forced to zero (padding_idx=0) -> row 0 output = bias only.
__global__ __launch_bounds__(256) void gemm_kernel(const float* __restrict__ A,
    const float* __restrict__ Wt, const float* __restrict__ bias,
    float* __restrict__ X, int M)
{
  __shared__ float As[16][68];   // [k][m], +4 pad
  __shared__ float Bs[16][68];   // [k][n]
  const int bm = blockIdx.x * 64;
  const int bn = blockIdx.y * 64;
  const int tid = threadIdx.x;
  const int tx = tid & 15, ty = tid >> 4;          // 16x16 thread grid, 4x4 micro-tile
  const int lr = tid >> 2, lk = (tid & 3) * 4;     // loader: 64 rows x 16 k, float4
  float acc[4][4] = {};
  for (int k0 = 0; k0 < IN_F; k0 += 16) {
    const int arow = bm + lr;
    float4 av = make_float4(0.f, 0.f, 0.f, 0.f);
    if (arow < M && arow != 0)
      av = *(const float4*)(A + (size_t)arow * IN_F + k0 + lk);
    As[lk+0][lr] = av.x; As[lk+1][lr] = av.y; As[lk+2][lr] = av.z; As[lk+3][lr] = av.w;
    const int brow = bn + lr;
    float4 bv = *(const float4*)(Wt + (size_t)brow * IN_F + k0 + lk);
    Bs[lk+0][lr] = bv.x; Bs[lk+1][lr] = bv.y; Bs[lk+2][lr] = bv.z; Bs[lk+3][lr] = bv.w;
    __syncthreads();
    #pragma unroll
    for (int kk = 0; kk < 16; ++kk) {
      float4 a4 = *(const float4*)&As[kk][ty * 4];
      float4 b4 = *(const float4*)&Bs[kk][tx * 4];
      float aa[4] = {a4.x, a4.y, a4.z, a4.w};
      float bb[4] = {b4.x, b4.y, b4.z, b4.w};
      #pragma unroll
      for (int i = 0; i < 4; ++i)
        #pragma unroll
        for (int j = 0; j < 4; ++j) acc[i][j] += aa[i] * bb[j];
    }
    __syncthreads();
  }
  #pragma unroll
  for (int i = 0; i < 4; ++i) {
    int row = bm + ty * 4 + i;
    if (row >= M) continue;
    int col = bn + tx * 4;
    float4 bz = *(const float4*)(bias + col);
    float4 o = make_float4(acc[i][0] + bz.x, acc[i][1] + bz.y,
                           acc[i][2] + bz.z, acc[i][3] + bz.w);
    *(float4*)(X + (size_t)row * OUT_F + col) = o;
  }
}

// ---------------- per-node attention projections s1 = X.a1, s2 = X.a2 ----------------
// one wave per node; lane l covers 8 consecutive elems, head = l>>4.
// sbuf layout: [node][0..3]=s1 per head, [4..7]=s2 per head (32B/node for gather locality)
__global__ __launch_bounds__(256) void score_kernel(const float* __restrict__ X,
    const float* __restrict__ a_attn, float* __restrict__ sbuf, int M)
{
  int node = blockIdx.x * 4 + (threadIdx.x >> 6);
  if (node >= M) return;
  int lane = threadIdx.x & 63;
  int hl = lane >> 4, o = (lane & 15) * 8;
  const float4* xr = (const float4*)(X + (size_t)node * OUT_F + hl * HID + o);
  const float4* a1 = (const float4*)(a_attn + hl * 2 * HID + o);
  const float4* a2 = (const float4*)(a_attn + hl * 2 * HID + HID + o);
  float4 x0 = xr[0], x1 = xr[1];
  float4 a10 = a1[0], a11 = a1[1];
  float4 a20 = a2[0], a21 = a2[1];
  float p1 = x0.x*a10.x + x0.y*a10.y + x0.z*a10.z + x0.w*a10.w
           + x1.x*a11.x + x1.y*a11.y + x1.z*a11.z + x1.w*a11.w;
  float p2 = x0.x*a20.x + x0.y*a20.y + x0.z*a20.z + x0.w*a20.w
           + x1.x*a21.x + x1.y*a21.y + x1.z*a21.z + x1.w*a21.w;
  #pragma unroll
  for (int off = 1; off < 16; off <<= 1) {
    p1 += __shfl_xor(p1, off, 64);
    p2 += __shfl_xor(p2, off, 64);
  }
  if ((lane & 15) == 0) {
    sbuf[(size_t)node * 8 + hl]     = p1;
    sbuf[(size_t)node * 8 + 4 + hl] = p2;
  }
}

// ---------------- CSR build ----------------
__global__ void hist_kernel(const int* __restrict__ src, int* __restrict__ count)
{
  int i = blockIdx.x * blockDim.x + threadIdx.x;
  if (i < NE) {
    int s = min(max(src[i], 0), N_NODES - 1);
    atomicAdd(&count[s], 1);
  }
}

__global__ void scan_kernel(const int* __restrict__ count, int* __restrict__ offset,
                            int* __restrict__ cursor, int n)
{
  __shared__ int wsum[16];
  __shared__ int carry_s;
  const int tid = threadIdx.x;
  const int lane = tid & 63, wid = tid >> 6;
  if (tid == 0) carry_s = 0;
  __syncthreads();
  for (int base = 0; base < n; base += 1024) {
    int idx = base + tid;
    int v = (idx < n) ? count[idx] : 0;
    int s = v;
    #pragma unroll
    for (int off = 1; off < 64; off <<= 1) {
      int t = __shfl_up(s, off, 64);
      if (lane >= off) s += t;
    }
    if (lane == 63) wsum[wid] = s;
    __syncthreads();
    if (wid == 0) {
      int wv = (lane < 16) ? wsum[lane] : 0;
      int ss = wv;
      #pragma unroll
      for (int off = 1; off < 16; off <<= 1) {
        int t = __shfl_up(ss, off, 64);
        if (lane >= off) ss += t;
      }
      if (lane < 16) wsum[lane] = ss - wv;  // exclusive wave offsets
    }
    __syncthreads();
    int excl = carry_s + wsum[wid] + (s - v);
    if (idx < n) { offset[idx] = excl; cursor[idx] = excl; }
    __syncthreads();
    if (tid == 1023) carry_s += wsum[15] + s;  // chunk total
    __syncthreads();
  }
}

__global__ void scatter_kernel(const int* __restrict__ src, const int* __restrict__ dst,
                               int* __restrict__ cursor, int* __restrict__ sdst)
{
  int i = blockIdx.x * blockDim.x + threadIdx.x;
  if (i < NE) {
    int s = min(max(src[i], 0), N_NODES - 1);
    int d = min(max(dst[i], 0), N_NODES - 1);
    int p = atomicAdd(&cursor[s], 1);
    sdst[p] = d;
  }
}

// ---------------- fused segment-softmax-agg + LayerNorm + ELU ----------------
// one block per node; wave h handles head h; lane holds out elems {2*lane, 2*lane+1}.
__global__ __launch_bounds__(256) void attn_kernel(const float* __restrict__ X,
    const float* __restrict__ sbuf, const int* __restrict__ offset,
    const int* __restrict__ count, const int* __restrict__ sdst,
    const float* __restrict__ gain, const float* __restrict__ bias,
    float* __restrict__ out)
{
  const int n = blockIdx.x;
  const int tid = threadIdx.x;
  const int h = tid >> 6, lane = tid & 63;
  const int start = offset[n];
  const int deg = count[n];
  const float s1v = sbuf[(size_t)n * 8 + h];
  const float inv_scale = 0.04419417382415922f;  // 1/sqrt(512)
  float2 acc = make_float2(0.f, 0.f);
  float rowsum = 0.f;
  for (int i = 0; i < deg; ++i) {
    int d = sdst[start + i];
    float s2v = sbuf[(size_t)d * 8 + 4 + h];
    float t = s1v + s2v;
    float lr = t >= 0.f ? t : ALPHA * t;
    float e = __expf(lr * inv_scale);
    rowsum += e;
    float2 xv = *(const float2*)(X + (size_t)d * OUT_F + h * HID + lane * 2);
    acc.x += e * xv.x;
    acc.y += e * xv.y;
  }
  float inv = (rowsum == 0.f) ? 1.f : 1.f / rowsum;
  float v0 = acc.x * inv, v1 = acc.y * inv;
  // block LayerNorm over 512 values (4 waves)
  float psum = v0 + v1, psq = v0 * v0 + v1 * v1;
  #pragma unroll
  for (int off = 32; off >= 1; off >>= 1) {
    psum += __shfl_xor(psum, off, 64);
    psq  += __shfl_xor(psq,  off, 64);
  }
  __shared__ float ssum[4], ssq[4];
  if (lane == 0) { ssum[h] = psum; ssq[h] = psq; }
  __syncthreads();
  float tot   = ssum[0] + ssum[1] + ssum[2] + ssum[3];
  float totsq = ssq[0]  + ssq[1]  + ssq[2]  + ssq[3];
  float mean = tot * (1.0f / OUT_F);
  float var  = fmaxf((totsq - OUT_F * mean * mean) * (1.0f / (OUT_F - 1)), 0.f);
  float inv_std = 1.0f / (sqrtf(var) + LN_EPS);
  int c0 = h * HID + lane * 2;
  float n0 = gain[c0]     * (v0 - mean) * inv_std + bias[c0];
  float n1 = gain[c0 + 1] * (v1 - mean) * inv_std + bias[c0 + 1];
  float o0 = n0 > 0.f ? n0 : expm1f(n0);
  float o1 = n1 > 0.f ? n1 : expm1f(n1);
  *(float2*)(out + (size_t)n * OUT_F + c0) = make_float2(o0, o1);
}

extern "C" void kernel_launch(void* const* d_in, const int* in_sizes, int n_in,
                              void* d_out, int out_size, void* d_ws, size_t ws_size,
                              hipStream_t stream)
{
  // inputs: 0 data (ignored), 1 edge [2,E] int, 2 embed_table [N,256] f32,
  //         3 W [4,128,256] f32, 4 b [4,128] f32, 5 a_attn [4,256] f32,
  //         6 ln_gain [512] f32, 7 ln_bias [512] f32
  const int*   edge   = (const int*)d_in[1];
  const float* embed  = (const float*)d_in[2];
  const float* W      = (const float*)d_in[3];
  const float* b      = (const float*)d_in[4];
  const float* a_attn = (const float*)d_in[5];
  const float* ln_g   = (const float*)d_in[6];
  const float* ln_b   = (const float*)d_in[7];
  float* out = (float*)d_out;

  char* ws = (char*)d_ws;
  size_t off = 0;
  auto alloc = [&](size_t bytes) -> void* {
    void* p = ws + off;
    off = (off + bytes + 255) & ~(size_t)255;
    return p;
  };
  float* X      = (float*)alloc((size_t)N_NODES * OUT_F * sizeof(float));  // 102.4 MB
  float* sbuf   = (float*)alloc((size_t)N_NODES * 8 * sizeof(float));      // 1.6 MB
  int*   count  = (int*)alloc((size_t)N_NODES * sizeof(int));
  int*   offs   = (int*)alloc((size_t)N_NODES * sizeof(int));
  int*   cursor = (int*)alloc((size_t)N_NODES * sizeof(int));
  int*   sdst   = (int*)alloc((size_t)NE * sizeof(int));                   // 3.2 MB

  const int* src = edge;
  const int* dst = edge + NE;

  hipMemsetAsync(count, 0, N_NODES * sizeof(int), stream);
  hist_kernel<<<(NE + 255) / 256, 256, 0, stream>>>(src, count);
  scan_kernel<<<1, 1024, 0, stream>>>(count, offs, cursor, N_NODES);
  scatter_kernel<<<(NE + 255) / 256, 256, 0, stream>>>(src, dst, cursor, sdst);

  dim3 gg((N_NODES + 63) / 64, OUT_F / 64);
  gemm_kernel<<<gg, 256, 0, stream>>>(embed, W, b, X, N_NODES);
  score_kernel<<<(N_NODES + 3) / 4, 256, 0, stream>>>(X, a_attn, sbuf, N_NODES);
  attn_kernel<<<N_NODES, 256, 0, stream>>>(X, sbuf, offs, count, sdst, ln_g, ln_b, out);
}

// Round 2
// 608.690 us; speedup vs baseline: 1.1933x; 1.1933x over previous
//
#include <hip/hip_runtime.h>
#include <math.h>

#define N_NODES 50000
#define IN_F    256
#define HID     128
#define HEADS   4
#define NE      800000
#define ALPHA   0.2f
#define LN_EPS  1e-6f
#define OUT_F   512   // HEADS*HID

typedef __attribute__((ext_vector_type(8))) short bf16x8;
typedef __attribute__((ext_vector_type(4))) float f32x4;

static __device__ __forceinline__ unsigned short f2bf(float f) {
  unsigned int u = __float_as_uint(f);
  unsigned int r = (u + 0x7FFFu + ((u >> 16) & 1u)) >> 16;
  return (unsigned short)r;
}
static __device__ __forceinline__ float bf2f(unsigned short h) {
  return __uint_as_float(((unsigned int)h) << 16);
}

// ---------------- fp32 -> bf16 conversion (emb with padding row 0 zeroed; W plain) ----
__global__ __launch_bounds__(256) void conv_kernel(const float* __restrict__ in,
    unsigned short* __restrict__ out, int n4, int zero_first64)
{
  int i = blockIdx.x * 256 + threadIdx.x;
  if (i >= n4) return;
  float4 v = ((const float4*)in)[i];
  if (zero_first64 && i < 64) v = make_float4(0.f, 0.f, 0.f, 0.f);  // row 0 (256 f) = 64 float4
  ushort4 o;
  o.x = f2bf(v.x); o.y = f2bf(v.y); o.z = f2bf(v.z); o.w = f2bf(v.w);
  ((ushort4*)out)[i] = o;
}

// ---------------- MFMA GEMM: X[m, n] = emb[m,:] . W[n,:] + b[n], bf16 in/out -----------
// Operand swap: A-operand = W rows (n,k), B-operand = emb rows (m,k).
// D[row=q*4+reg -> n within tile][col=r -> m]; lane stores 4 consecutive n as bf16x4.
__global__ __launch_bounds__(256) void gemm_mfma(const unsigned short* __restrict__ A,
    const unsigned short* __restrict__ W, const float* __restrict__ bias,
    unsigned short* __restrict__ X, int M)
{
  const int w = threadIdx.x >> 6, lane = threadIdx.x & 63;
  const int r = lane & 15, q = lane >> 4;
  const int m_base = blockIdx.x * 64 + w * 16;
  const int row = m_base + r;
  const int rowc = min(row, M - 1);
  f32x4 acc[32] = {};
  const unsigned short* arow = A + (size_t)rowc * IN_F;
  for (int k0 = 0; k0 < IN_F; k0 += 32) {
    bf16x8 bfrag = *(const bf16x8*)(arow + k0 + q * 8);
    #pragma unroll
    for (int nt = 0; nt < 32; ++nt) {
      bf16x8 afrag = *(const bf16x8*)(W + (size_t)(nt * 16 + r) * IN_F + k0 + q * 8);
      acc[nt] = __builtin_amdgcn_mfma_f32_16x16x32_bf16(afrag, bfrag, acc[nt], 0, 0, 0);
    }
  }
  if (row < M) {
    #pragma unroll
    for (int nt = 0; nt < 32; ++nt) {
      int n0 = nt * 16 + q * 4;
      float4 bz = *(const float4*)(bias + n0);
      ushort4 o;
      o.x = f2bf(acc[nt][0] + bz.x);
      o.y = f2bf(acc[nt][1] + bz.y);
      o.z = f2bf(acc[nt][2] + bz.z);
      o.w = f2bf(acc[nt][3] + bz.w);
      *(ushort4*)(X + (size_t)row * OUT_F + n0) = o;
    }
  }
}

// ---------------- per-node projections s1 = X.a1, s2 = X.a2 (bf16 X) ----------------
__global__ __launch_bounds__(256) void score_kernel(const unsigned short* __restrict__ X,
    const float* __restrict__ a_attn, float* __restrict__ sbuf, int M)
{
  int node = blockIdx.x * 4 + (threadIdx.x >> 6);
  if (node >= M) return;
  int lane = threadIdx.x & 63;
  int hl = lane >> 4, o = (lane & 15) * 8;
  const unsigned short* xp = X + (size_t)node * OUT_F + hl * HID + o;
  ushort4 xa = *(const ushort4*)xp;
  ushort4 xb = *(const ushort4*)(xp + 4);
  float xv[8] = { bf2f(xa.x), bf2f(xa.y), bf2f(xa.z), bf2f(xa.w),
                  bf2f(xb.x), bf2f(xb.y), bf2f(xb.z), bf2f(xb.w) };
  const float* a1 = a_attn + hl * 2 * HID + o;
  const float* a2 = a_attn + hl * 2 * HID + HID + o;
  float p1 = 0.f, p2 = 0.f;
  #pragma unroll
  for (int j = 0; j < 8; ++j) { p1 += xv[j] * a1[j]; p2 += xv[j] * a2[j]; }
  #pragma unroll
  for (int off = 1; off < 16; off <<= 1) {
    p1 += __shfl_xor(p1, off, 64);
    p2 += __shfl_xor(p2, off, 64);
  }
  if ((lane & 15) == 0) {
    sbuf[(size_t)node * 8 + hl]     = p1;
    sbuf[(size_t)node * 8 + 4 + hl] = p2;
  }
}

// ---------------- CSR build ----------------
__global__ void hist_kernel(const int* __restrict__ src, int* __restrict__ count)
{
  int i = blockIdx.x * blockDim.x + threadIdx.x;
  if (i < NE) {
    int s = min(max(src[i], 0), N_NODES - 1);
    atomicAdd(&count[s], 1);
  }
}

__global__ void scan_kernel(const int* __restrict__ count, int* __restrict__ offset,
                            int* __restrict__ cursor, int n)
{
  __shared__ int wsum[16];
  __shared__ int carry_s;
  const int tid = threadIdx.x;
  const int lane = tid & 63, wid = tid >> 6;
  if (tid == 0) carry_s = 0;
  __syncthreads();
  for (int base = 0; base < n; base += 1024) {
    int idx = base + tid;
    int v = (idx < n) ? count[idx] : 0;
    int s = v;
    #pragma unroll
    for (int off = 1; off < 64; off <<= 1) {
      int t = __shfl_up(s, off, 64);
      if (lane >= off) s += t;
    }
    if (lane == 63) wsum[wid] = s;
    __syncthreads();
    if (wid == 0) {
      int wv = (lane < 16) ? wsum[lane] : 0;
      int ss = wv;
      #pragma unroll
      for (int off = 1; off < 16; off <<= 1) {
        int t = __shfl_up(ss, off, 64);
        if (lane >= off) ss += t;
      }
      if (lane < 16) wsum[lane] = ss - wv;  // exclusive wave offsets
    }
    __syncthreads();
    int excl = carry_s + wsum[wid] + (s - v);
    if (idx < n) { offset[idx] = excl; cursor[idx] = excl; }
    __syncthreads();
    if (tid == 1023) carry_s += wsum[15] + s;  // chunk total
    __syncthreads();
  }
}

__global__ void scatter_kernel(const int* __restrict__ src, const int* __restrict__ dst,
                               int* __restrict__ cursor, int* __restrict__ sdst)
{
  int i = blockIdx.x * blockDim.x + threadIdx.x;
  if (i < NE) {
    int s = min(max(src[i], 0), N_NODES - 1);
    int d = min(max(dst[i], 0), N_NODES - 1);
    int p = atomicAdd(&cursor[s], 1);
    sdst[p] = d;
  }
}

// ---------------- fused segment-softmax-agg + LayerNorm + ELU (bf16 X gather) ---------
__global__ __launch_bounds__(256) void attn_kernel(const unsigned short* __restrict__ X,
    const float* __restrict__ sbuf, const int* __restrict__ offset,
    const int* __restrict__ count, const int* __restrict__ sdst,
    const float* __restrict__ gain, const float* __restrict__ bias,
    float* __restrict__ out)
{
  const int n = blockIdx.x;
  const int tid = threadIdx.x;
  const int h = tid >> 6, lane = tid & 63;
  const int start = offset[n];
  const int deg = count[n];
  const float s1v = sbuf[(size_t)n * 8 + h];
  const float inv_scale = 0.04419417382415922f;  // 1/sqrt(512)
  const int c0 = h * HID + lane * 2;
  float2 acc = make_float2(0.f, 0.f);
  float rowsum = 0.f;
  int i = 0;
  for (; i + 2 <= deg; i += 2) {
    int d0 = sdst[start + i], d1 = sdst[start + i + 1];
    float s20 = sbuf[(size_t)d0 * 8 + 4 + h];
    float s21 = sbuf[(size_t)d1 * 8 + 4 + h];
    unsigned int xv0 = *(const unsigned int*)(X + (size_t)d0 * OUT_F + c0);
    unsigned int xv1 = *(const unsigned int*)(X + (size_t)d1 * OUT_F + c0);
    float t0 = s1v + s20, t1 = s1v + s21;
    float lr0 = t0 >= 0.f ? t0 : ALPHA * t0;
    float lr1 = t1 >= 0.f ? t1 : ALPHA * t1;
    float e0 = __expf(lr0 * inv_scale);
    float e1 = __expf(lr1 * inv_scale);
    rowsum += e0 + e1;
    acc.x += e0 * bf2f((unsigned short)(xv0 & 0xFFFF)) + e1 * bf2f((unsigned short)(xv1 & 0xFFFF));
    acc.y += e0 * bf2f((unsigned short)(xv0 >> 16))    + e1 * bf2f((unsigned short)(xv1 >> 16));
  }
  if (i < deg) {
    int d0 = sdst[start + i];
    float s20 = sbuf[(size_t)d0 * 8 + 4 + h];
    unsigned int xv0 = *(const unsigned int*)(X + (size_t)d0 * OUT_F + c0);
    float t0 = s1v + s20;
    float lr0 = t0 >= 0.f ? t0 : ALPHA * t0;
    float e0 = __expf(lr0 * inv_scale);
    rowsum += e0;
    acc.x += e0 * bf2f((unsigned short)(xv0 & 0xFFFF));
    acc.y += e0 * bf2f((unsigned short)(xv0 >> 16));
  }
  float inv = (rowsum == 0.f) ? 1.f : 1.f / rowsum;
  float v0 = acc.x * inv, v1 = acc.y * inv;
  float psum = v0 + v1, psq = v0 * v0 + v1 * v1;
  #pragma unroll
  for (int off = 32; off >= 1; off >>= 1) {
    psum += __shfl_xor(psum, off, 64);
    psq  += __shfl_xor(psq,  off, 64);
  }
  __shared__ float ssum[4], ssq[4];
  if (lane == 0) { ssum[h] = psum; ssq[h] = psq; }
  __syncthreads();
  float tot   = ssum[0] + ssum[1] + ssum[2] + ssum[3];
  float totsq = ssq[0]  + ssq[1]  + ssq[2]  + ssq[3];
  float mean = tot * (1.0f / OUT_F);
  float var  = fmaxf((totsq - OUT_F * mean * mean) * (1.0f / (OUT_F - 1)), 0.f);
  float inv_std = 1.0f / (sqrtf(var) + LN_EPS);
  float n0 = gain[c0]     * (v0 - mean) * inv_std + bias[c0];
  float n1 = gain[c0 + 1] * (v1 - mean) * inv_std + bias[c0 + 1];
  float o0 = n0 > 0.f ? n0 : expm1f(n0);
  float o1 = n1 > 0.f ? n1 : expm1f(n1);
  *(float2*)(out + (size_t)n * OUT_F + c0) = make_float2(o0, o1);
}

extern "C" void kernel_launch(void* const* d_in, const int* in_sizes, int n_in,
                              void* d_out, int out_size, void* d_ws, size_t ws_size,
                              hipStream_t stream)
{
  const int*   edge   = (const int*)d_in[1];
  const float* embed  = (const float*)d_in[2];
  const float* W      = (const float*)d_in[3];
  const float* b      = (const float*)d_in[4];
  const float* a_attn = (const float*)d_in[5];
  const float* ln_g   = (const float*)d_in[6];
  const float* ln_b   = (const float*)d_in[7];
  float* out = (float*)d_out;

  char* ws = (char*)d_ws;
  size_t off = 0;
  auto alloc = [&](size_t bytes) -> void* {
    void* p = ws + off;
    off = (off + bytes + 255) & ~(size_t)255;
    return p;
  };
  unsigned short* embB = (unsigned short*)alloc((size_t)N_NODES * IN_F * sizeof(unsigned short)); // 25.6MB
  unsigned short* WB   = (unsigned short*)alloc((size_t)OUT_F * IN_F * sizeof(unsigned short));   // 0.25MB
  unsigned short* X    = (unsigned short*)alloc((size_t)N_NODES * OUT_F * sizeof(unsigned short));// 51.2MB
  float* sbuf   = (float*)alloc((size_t)N_NODES * 8 * sizeof(float));
  int*   count  = (int*)alloc((size_t)N_NODES * sizeof(int));
  int*   offs   = (int*)alloc((size_t)N_NODES * sizeof(int));
  int*   cursor = (int*)alloc((size_t)N_NODES * sizeof(int));
  int*   sdst   = (int*)alloc((size_t)NE * sizeof(int));

  const int* src = edge;
  const int* dst = edge + NE;

  hipMemsetAsync(count, 0, N_NODES * sizeof(int), stream);
  // CSR build
  hist_kernel<<<(NE + 255) / 256, 256, 0, stream>>>(src, count);
  scan_kernel<<<1, 1024, 0, stream>>>(count, offs, cursor, N_NODES);
  scatter_kernel<<<(NE + 255) / 256, 256, 0, stream>>>(src, dst, cursor, sdst);

  // bf16 conversions
  int n4e = N_NODES * IN_F / 4;
  conv_kernel<<<(n4e + 255) / 256, 256, 0, stream>>>(embed, embB, n4e, 1);
  int n4w = OUT_F * IN_F / 4;
  conv_kernel<<<(n4w + 255) / 256, 256, 0, stream>>>(W, WB, n4w, 0);

  // X = emb @ W^T + b  (bf16 MFMA)
  gemm_mfma<<<(N_NODES + 63) / 64, 256, 0, stream>>>(embB, WB, b, X, N_NODES);
  score_kernel<<<(N_NODES + 3) / 4, 256, 0, stream>>>(X, a_attn, sbuf, N_NODES);
  attn_kernel<<<N_NODES, 256, 0, stream>>>(X, sbuf, offs, count, sdst, ln_g, ln_b, out);
}

// Round 4
// 500.378 us; speedup vs baseline: 1.4516x; 1.2165x over previous
//
#include <hip/hip_runtime.h>
#include <math.h>

#define N_NODES 50000
#define IN_F    256
#define HID     128
#define HEADS   4
#define NE      800000
#define ALPHA   0.2f
#define LN_EPS  1e-6f
#define OUT_F   512   // HEADS*HID
#define INV_SCALE 0.04419417382415922f  // 1/sqrt(512)

typedef __attribute__((ext_vector_type(8))) short bf16x8;
typedef __attribute__((ext_vector_type(4))) float f32x4;

static __device__ __forceinline__ unsigned short f2bf(float f) {
  unsigned int u = __float_as_uint(f);
  unsigned int r = (u + 0x7FFFu + ((u >> 16) & 1u)) >> 16;
  return (unsigned short)r;
}
static __device__ __forceinline__ float bf2f(unsigned short h) {
  return __uint_as_float(((unsigned int)h) << 16);
}

// ---------------- fp32 -> bf16 conversion (emb row 0 zeroed for padding_idx) ---------
__global__ __launch_bounds__(256) void conv_kernel(const float* __restrict__ in,
    unsigned short* __restrict__ out, int n4, int zero_first64)
{
  int i = blockIdx.x * 256 + threadIdx.x;
  if (i >= n4) return;
  float4 v = ((const float4*)in)[i];
  if (zero_first64 && i < 64) v = make_float4(0.f, 0.f, 0.f, 0.f);
  ushort4 o;
  o.x = f2bf(v.x); o.y = f2bf(v.y); o.z = f2bf(v.z); o.w = f2bf(v.w);
  ((ushort4*)out)[i] = o;
}

// ---------------- MFMA GEMM + fused score projections -------------------------------
// Block: 256 thr (4 waves), 64 emb rows. Wave w == head w (cols w*128..w*128+127).
// LDS holds the k-slice of W (512x32) and A (64x32) in MFMA fragment order:
// chunk c = [tile][q][r] of 8 halfwords -> both ds_write_b128 and ds_read_b128 are
// lane-contiguous (conflict-free).
__global__ __launch_bounds__(256, 2) void gemm_fused(
    const unsigned short* __restrict__ embB, const unsigned short* __restrict__ WB,
    const float* __restrict__ bias, const float* __restrict__ a_attn,
    unsigned short* __restrict__ X, float* __restrict__ sbuf, int M)
{
  __shared__ unsigned short Wl[32 * 512];  // 32 KB: [nt][q][r][j]
  __shared__ unsigned short Al[4 * 512];   // 4 KB : [mb][q][r][j]
  const int tid = threadIdx.x;
  const int w = tid >> 6, lane = tid & 63;
  const int r = lane & 15, q = lane >> 4;
  const int bm = blockIdx.x * 64;
  f32x4 acc[8][4] = {};
  for (int k0 = 0; k0 < IN_F; k0 += 32) {
    __syncthreads();
    {  // stage A tile: 256 x 16B chunks, one per thread
      int c = tid;
      int rr = c & 15, qq = (c >> 4) & 3, mb = c >> 6;
      int row = min(bm + mb * 16 + rr, M - 1);
      *(bf16x8*)(Al + c * 8) = *(const bf16x8*)(embB + (size_t)row * IN_F + k0 + qq * 8);
    }
    #pragma unroll
    for (int i2 = 0; i2 < 8; ++i2) {  // stage W slice: 2048 chunks, 8 per thread
      int c = i2 * 256 + tid;
      int rr = c & 15, qq = (c >> 4) & 3, nt = c >> 6;
      *(bf16x8*)(Wl + c * 8) = *(const bf16x8*)(WB + (size_t)(nt * 16 + rr) * IN_F + k0 + qq * 8);
    }
    __syncthreads();
    bf16x8 bfrag[4];
    #pragma unroll
    for (int mb = 0; mb < 4; ++mb)
      bfrag[mb] = *(const bf16x8*)(Al + mb * 512 + q * 128 + r * 8);
    #pragma unroll
    for (int t = 0; t < 8; ++t) {
      bf16x8 afrag = *(const bf16x8*)(Wl + (w * 8 + t) * 512 + q * 128 + r * 8);
      #pragma unroll
      for (int mb = 0; mb < 4; ++mb)
        acc[t][mb] = __builtin_amdgcn_mfma_f32_16x16x32_bf16(afrag, bfrag[mb], acc[t][mb], 0, 0, 0);
    }
  }
  // epilogue: add bias, store bf16 X, accumulate fused score projections
  const float* a1 = a_attn + w * 2 * HID;
  const float* a2 = a1 + HID;
  #pragma unroll
  for (int mb = 0; mb < 4; ++mb) {
    int m = bm + mb * 16 + r;
    float p1 = 0.f, p2 = 0.f;
    #pragma unroll
    for (int t = 0; t < 8; ++t) {
      int nloc = t * 16 + q * 4;        // col within head
      int n = w * HID + nloc;           // global col
      float4 bz = *(const float4*)(bias + n);
      float x0 = acc[t][mb][0] + bz.x;
      float x1 = acc[t][mb][1] + bz.y;
      float x2 = acc[t][mb][2] + bz.z;
      float x3 = acc[t][mb][3] + bz.w;
      float4 av1 = *(const float4*)(a1 + nloc);
      float4 av2 = *(const float4*)(a2 + nloc);
      p1 += x0 * av1.x + x1 * av1.y + x2 * av1.z + x3 * av1.w;
      p2 += x0 * av2.x + x1 * av2.y + x2 * av2.z + x3 * av2.w;
      if (m < M) {
        ushort4 o = make_ushort4(f2bf(x0), f2bf(x1), f2bf(x2), f2bf(x3));
        *(ushort4*)(X + (size_t)m * OUT_F + n) = o;
      }
    }
    p1 += __shfl_xor(p1, 16, 64); p1 += __shfl_xor(p1, 32, 64);
    p2 += __shfl_xor(p2, 16, 64); p2 += __shfl_xor(p2, 32, 64);
    if (q == 0 && m < M) {
      sbuf[(size_t)m * 8 + w]     = p1;
      sbuf[(size_t)m * 8 + 4 + w] = p2;
    }
  }
}

// ---------------- CSR build ----------------
__global__ void hist_kernel(const int* __restrict__ src, int* __restrict__ count)
{
  int i = blockIdx.x * blockDim.x + threadIdx.x;
  if (i < NE) {
    int s = min(max(src[i], 0), N_NODES - 1);
    atomicAdd(&count[s], 1);
  }
}

__global__ void scan_kernel(const int* __restrict__ count, int* __restrict__ offset,
                            int* __restrict__ cursor, int n)
{
  __shared__ int wsum[16];
  __shared__ int carry_s;
  const int tid = threadIdx.x;
  const int lane = tid & 63, wid = tid >> 6;
  if (tid == 0) carry_s = 0;
  __syncthreads();
  for (int base = 0; base < n; base += 1024) {
    int idx = base + tid;
    int v = (idx < n) ? count[idx] : 0;
    int s = v;
    #pragma unroll
    for (int off = 1; off < 64; off <<= 1) {
      int t = __shfl_up(s, off, 64);
      if (lane >= off) s += t;
    }
    if (lane == 63) wsum[wid] = s;
    __syncthreads();
    if (wid == 0) {
      int wv = (lane < 16) ? wsum[lane] : 0;
      int ss = wv;
      #pragma unroll
      for (int off = 1; off < 16; off <<= 1) {
        int t = __shfl_up(ss, off, 64);
        if (lane >= off) ss += t;
      }
      if (lane < 16) wsum[lane] = ss - wv;
    }
    __syncthreads();
    int excl = carry_s + wsum[wid] + (s - v);
    if (idx < n) { offset[idx] = excl; cursor[idx] = excl; }
    __syncthreads();
    if (tid == 1023) carry_s += wsum[15] + s;
    __syncthreads();
  }
}

// scatter + per-edge-per-head exp(leakyrelu(s1[src]+s2[dst])/scale), computed ONCE
__global__ void scatter_exp(const int* __restrict__ src, const int* __restrict__ dst,
                            int* __restrict__ cursor, const float* __restrict__ sbuf,
                            int* __restrict__ sdst, float4* __restrict__ ebuf)
{
  int i = blockIdx.x * blockDim.x + threadIdx.x;
  if (i >= NE) return;
  int s = min(max(src[i], 0), N_NODES - 1);
  int d = min(max(dst[i], 0), N_NODES - 1);
  int p = atomicAdd(&cursor[s], 1);
  sdst[p] = d;
  float4 s1 = *(const float4*)(sbuf + (size_t)s * 8);
  float4 s2 = *(const float4*)(sbuf + (size_t)d * 8 + 4);
  float t0 = s1.x + s2.x, t1 = s1.y + s2.y, t2 = s1.z + s2.z, t3 = s1.w + s2.w;
  float4 e;
  e.x = __expf((t0 >= 0.f ? t0 : ALPHA * t0) * INV_SCALE);
  e.y = __expf((t1 >= 0.f ? t1 : ALPHA * t1) * INV_SCALE);
  e.z = __expf((t2 >= 0.f ? t2 : ALPHA * t2) * INV_SCALE);
  e.w = __expf((t3 >= 0.f ? t3 : ALPHA * t3) * INV_SCALE);
  ebuf[p] = e;
}

// ---------------- segment aggregate (precomputed e) + LayerNorm + ELU ----------------
__global__ __launch_bounds__(256) void attn_kernel(const unsigned short* __restrict__ X,
    const float* __restrict__ ebuf, const int* __restrict__ offset,
    const int* __restrict__ count, const int* __restrict__ sdst,
    const float* __restrict__ gain, const float* __restrict__ bias,
    float* __restrict__ out)
{
  const int n = blockIdx.x;
  const int tid = threadIdx.x;
  const int h = tid >> 6, lane = tid & 63;
  const int start = offset[n];
  const int deg = count[n];
  const int c0 = h * HID + lane * 2;
  float2 acc = make_float2(0.f, 0.f);
  float rowsum = 0.f;
  int i = 0;
  for (; i + 2 <= deg; i += 2) {
    int d0 = sdst[start + i], d1 = sdst[start + i + 1];
    float e0 = ebuf[(size_t)(start + i) * 4 + h];
    float e1 = ebuf[(size_t)(start + i + 1) * 4 + h];
    unsigned int xv0 = *(const unsigned int*)(X + (size_t)d0 * OUT_F + c0);
    unsigned int xv1 = *(const unsigned int*)(X + (size_t)d1 * OUT_F + c0);
    rowsum += e0 + e1;
    acc.x += e0 * bf2f((unsigned short)(xv0 & 0xFFFF)) + e1 * bf2f((unsigned short)(xv1 & 0xFFFF));
    acc.y += e0 * bf2f((unsigned short)(xv0 >> 16))    + e1 * bf2f((unsigned short)(xv1 >> 16));
  }
  if (i < deg) {
    int d0 = sdst[start + i];
    float e0 = ebuf[(size_t)(start + i) * 4 + h];
    unsigned int xv0 = *(const unsigned int*)(X + (size_t)d0 * OUT_F + c0);
    rowsum += e0;
    acc.x += e0 * bf2f((unsigned short)(xv0 & 0xFFFF));
    acc.y += e0 * bf2f((unsigned short)(xv0 >> 16));
  }
  float inv = (rowsum == 0.f) ? 1.f : 1.f / rowsum;
  float v0 = acc.x * inv, v1 = acc.y * inv;
  float psum = v0 + v1, psq = v0 * v0 + v1 * v1;
  #pragma unroll
  for (int off = 32; off >= 1; off >>= 1) {
    psum += __shfl_xor(psum, off, 64);
    psq  += __shfl_xor(psq,  off, 64);
  }
  __shared__ float ssum[4], ssq[4];
  if (lane == 0) { ssum[h] = psum; ssq[h] = psq; }
  __syncthreads();
  float tot   = ssum[0] + ssum[1] + ssum[2] + ssum[3];
  float totsq = ssq[0]  + ssq[1]  + ssq[2]  + ssq[3];
  float mean = tot * (1.0f / OUT_F);
  float var  = fmaxf((totsq - OUT_F * mean * mean) * (1.0f / (OUT_F - 1)), 0.f);
  float inv_std = 1.0f / (sqrtf(var) + LN_EPS);
  float n0 = gain[c0]     * (v0 - mean) * inv_std + bias[c0];
  float n1 = gain[c0 + 1] * (v1 - mean) * inv_std + bias[c0 + 1];
  float o0 = n0 > 0.f ? n0 : expm1f(n0);
  float o1 = n1 > 0.f ? n1 : expm1f(n1);
  *(float2*)(out + (size_t)n * OUT_F + c0) = make_float2(o0, o1);
}

extern "C" void kernel_launch(void* const* d_in, const int* in_sizes, int n_in,
                              void* d_out, int out_size, void* d_ws, size_t ws_size,
                              hipStream_t stream)
{
  const int*   edge   = (const int*)d_in[1];
  const float* embed  = (const float*)d_in[2];
  const float* W      = (const float*)d_in[3];
  const float* b      = (const float*)d_in[4];
  const float* a_attn = (const float*)d_in[5];
  const float* ln_g   = (const float*)d_in[6];
  const float* ln_b   = (const float*)d_in[7];
  float* out = (float*)d_out;

  char* ws = (char*)d_ws;
  size_t off = 0;
  auto alloc = [&](size_t bytes) -> void* {
    void* p = ws + off;
    off = (off + bytes + 255) & ~(size_t)255;
    return p;
  };
  unsigned short* embB = (unsigned short*)alloc((size_t)N_NODES * IN_F * sizeof(unsigned short));
  unsigned short* WB   = (unsigned short*)alloc((size_t)OUT_F * IN_F * sizeof(unsigned short));
  unsigned short* X    = (unsigned short*)alloc((size_t)N_NODES * OUT_F * sizeof(unsigned short));
  float* sbuf   = (float*)alloc((size_t)N_NODES * 8 * sizeof(float));
  int*   count  = (int*)alloc((size_t)N_NODES * sizeof(int));
  int*   offs   = (int*)alloc((size_t)N_NODES * sizeof(int));
  int*   cursor = (int*)alloc((size_t)N_NODES * sizeof(int));
  int*   sdst   = (int*)alloc((size_t)NE * sizeof(int));
  float* ebuf   = (float*)alloc((size_t)NE * 4 * sizeof(float));

  const int* src = edge;
  const int* dst = edge + NE;

  // CSR histogram+scan (independent of GEMM)
  (void)hipMemsetAsync(count, 0, N_NODES * sizeof(int), stream);
  hist_kernel<<<(NE + 255) / 256, 256, 0, stream>>>(src, count);
  scan_kernel<<<1, 1024, 0, stream>>>(count, offs, cursor, N_NODES);

  // bf16 conversions
  int n4e = N_NODES * IN_F / 4;
  conv_kernel<<<(n4e + 255) / 256, 256, 0, stream>>>(embed, embB, n4e, 1);
  int n4w = OUT_F * IN_F / 4;
  conv_kernel<<<(n4w + 255) / 256, 256, 0, stream>>>(W, WB, n4w, 0);

  // X = emb @ W^T + b (bf16 MFMA) with fused s1/s2 projections
  gemm_fused<<<(N_NODES + 63) / 64, 256, 0, stream>>>(embB, WB, b, a_attn, X, sbuf, N_NODES);

  // CSR scatter with fused per-edge exp
  scatter_exp<<<(NE + 255) / 256, 256, 0, stream>>>(src, dst, cursor, sbuf, sdst,
                                                    (float4*)ebuf);

  // aggregation + LayerNorm + ELU
  attn_kernel<<<N_NODES, 256, 0, stream>>>(X, ebuf, offs, count, sdst, ln_g, ln_b, out);
}